// Round 2
// baseline (16274.236 us; speedup 1.0000x reference)
//
#include <hip/hip_runtime.h>
#include <hip/hip_bf16.h>
#include <cstdint>
#include <cstddef>

typedef __hip_bfloat16 bf16;

static __device__ __forceinline__ float bits_to_f32(uint32_t u) {
    union { uint32_t u; float f; } c; c.u = u; return c.f;
}

// ---------------------------------------------------------------------------
// Cayley: for 128 matrices (64 L, 64 R): X = (I+S)^-1 (I-S), S = skew - skew^T
// Gauss-Jordan, no pivoting (I+S has PD symmetric part -> stable).
// Block b: 256 threads, LDS 64x129 augmented matrix [I+S | I-S].
// ---------------------------------------------------------------------------
__global__ __launch_bounds__(256) void cayley_kernel(
    const float* __restrict__ Ls, const float* __restrict__ Rs,
    float* __restrict__ Lout, float* __restrict__ Rout)
{
    __shared__ float M[64 * 129];
    int b = blockIdx.x;
    const float* src = (b < 64) ? (Ls + (size_t)b * 4096) : (Rs + (size_t)(b - 64) * 4096);
    float* dst       = (b < 64) ? (Lout + (size_t)b * 4096) : (Rout + (size_t)(b - 64) * 4096);
    int tid = threadIdx.x;
    int r  = tid >> 2;          // row 0..63
    int c0 = (tid & 3) * 32;    // column block start

    for (int cc = 0; cc < 32; ++cc) {
        int c = c0 + cc;
        int jj = c & 63;
        float S = src[r * 64 + jj] - src[jj * 64 + r];
        float ident = (r == jj) ? 1.0f : 0.0f;
        M[r * 129 + c] = (c < 64) ? (ident + S) : (ident - S);
    }
    __syncthreads();

    for (int p = 0; p < 64; ++p) {
        if (r == p) {
            float pinv = 1.0f / M[p * 129 + p];   // lockstep read in-wave before writes
            for (int cc = 0; cc < 32; ++cc) M[p * 129 + c0 + cc] *= pinv;
        }
        __syncthreads();
        float f = M[r * 129 + p];
        __syncthreads();
        if (r != p) {
            for (int cc = 0; cc < 32; ++cc) M[r * 129 + c0 + cc] -= f * M[p * 129 + c0 + cc];
        }
        __syncthreads();
    }
    for (int cc = 0; cc < 32; ++cc) {
        int c = c0 + cc;
        if (c >= 64) dst[r * 64 + (c - 64)] = M[r * 129 + c];
    }
}

// ---------------------------------------------------------------------------
// Gates: alpha[m][k], beta[m][k] = sigmoid(u[m] . Wg_w[g] + Wg_b[g]),
// m = a*2048 + t. Block = (t-chunk of 8, a), 256 threads. u chunk in LDS.
// ---------------------------------------------------------------------------
__global__ __launch_bounds__(256) void gates_kernel(
    const float* __restrict__ u, const float* __restrict__ Wg_w,
    const float* __restrict__ Wg_b,
    float* __restrict__ alpha, float* __restrict__ beta)
{
    __shared__ float us[8 * 1024];
    int tc = blockIdx.x, a = blockIdx.y;
    int tid = threadIdx.x;
    const float4* u4 = (const float4*)(u + ((size_t)a * 2048 + (size_t)tc * 8) * 1024);
    float4* us4 = (float4*)us;
    for (int i = tid; i < 8 * 256; i += 256) us4[i] = u4[i];
    __syncthreads();

    int g  = tid & 127;
    int th = tid >> 7;
    const float4* w4 = (const float4*)(Wg_w + (size_t)g * 1024);
    float wb = Wg_b[g];
    for (int tl = th; tl < 8; tl += 2) {
        const float4* x4 = (const float4*)(us + tl * 1024);
        float s = 0.f;
        for (int q = 0; q < 256; ++q) {
            float4 w = w4[q], x = x4[q];
            s += w.x * x.x + w.y * x.y + w.z * x.z + w.w * x.w;
        }
        s += wb;
        float sig = 1.0f / (1.0f + __expf(-s));
        size_t m = (size_t)a * 2048 + (size_t)tc * 8 + tl;
        if (g < 64) alpha[m * 64 + g] = sig;
        else        beta [m * 64 + (g - 64)] = sig;
    }
}

// ---------------------------------------------------------------------------
// GEMM NT: C[r][n] = A[r][:] . B[n][:] (+ bias[n]) (+ Dvec[n]*Uext[row][n])
// Local rows r in [0, 64*gridDim.y); MAP_A / MAP_C remap local chunk rows to
// global rows:  g = (r/seg)*tstride + t0 + (r%seg).  Tiles never straddle a
// segment (64 | seg). f32 accumulate; A may be bf16; output may be bf16.
// 64x64 tile, BK=16, 256 threads, 4x4 per thread.
// ---------------------------------------------------------------------------
template<int AT_BF16, int OT_BF16, int MAP_A, int MAP_C>
__global__ __launch_bounds__(256) void gemm_nt_kernel(
    const void* __restrict__ Ap, const float* __restrict__ B,
    const float* __restrict__ bias, void* __restrict__ Cp,
    int N, int K,
    const float* __restrict__ Dvec, const float* __restrict__ Uext,
    int t0, int seg, int tstride)
{
    __shared__ float As[16][68];
    __shared__ float Bs[16][68];
    int bx = blockIdx.x, by = blockIdx.y;
    int tid = threadIdx.x;
    int tx = tid & 15, ty = tid >> 4;
    int lr = tid >> 2, lk = (tid & 3) << 2;
    float acc[4][4] = {};

    int aloc = by * 64 + lr;
    int arow_i = MAP_A ? ((aloc / seg) * tstride + t0 + (aloc % seg)) : aloc;
    const size_t arow = (size_t)arow_i * K;
    const size_t brow = (size_t)(bx * 64 + lr) * K;

    for (int k0 = 0; k0 < K; k0 += 16) {
        float a0, a1, a2, a3;
        if constexpr (AT_BF16) {
            const uint2 w = *(const uint2*)((const uint16_t*)Ap + arow + k0 + lk);
            a0 = bits_to_f32(w.x << 16); a1 = bits_to_f32(w.x & 0xffff0000u);
            a2 = bits_to_f32(w.y << 16); a3 = bits_to_f32(w.y & 0xffff0000u);
        } else {
            const float4 v = *(const float4*)((const float*)Ap + arow + k0 + lk);
            a0 = v.x; a1 = v.y; a2 = v.z; a3 = v.w;
        }
        As[lk + 0][lr] = a0; As[lk + 1][lr] = a1;
        As[lk + 2][lr] = a2; As[lk + 3][lr] = a3;
        const float4 v = *(const float4*)(B + brow + k0 + lk);
        Bs[lk + 0][lr] = v.x; Bs[lk + 1][lr] = v.y;
        Bs[lk + 2][lr] = v.z; Bs[lk + 3][lr] = v.w;
        __syncthreads();
        #pragma unroll
        for (int kk = 0; kk < 16; ++kk) {
            float4 avv = *(const float4*)&As[kk][ty << 2];
            float4 bvv = *(const float4*)&Bs[kk][tx << 2];
            float va[4] = {avv.x, avv.y, avv.z, avv.w};
            float vb[4] = {bvv.x, bvv.y, bvv.z, bvv.w};
            #pragma unroll
            for (int i = 0; i < 4; ++i)
                #pragma unroll
                for (int j = 0; j < 4; ++j)
                    acc[i][j] += va[i] * vb[j];
        }
        __syncthreads();
    }

    for (int i = 0; i < 4; ++i) {
        int mloc = by * 64 + (ty << 2) + i;
        int mg = MAP_C ? ((mloc / seg) * tstride + t0 + (mloc % seg)) : mloc;
        for (int j = 0; j < 4; ++j) {
            int n = bx * 64 + (tx << 2) + j;
            float val = acc[i][j];
            if (bias) val += bias[n];
            if (Dvec) val += Dvec[n] * Uext[(size_t)mg * N + n];
            if constexpr (OT_BF16) ((bf16*)Cp)[(size_t)mg * N + n] = __float2bfloat16(val);
            else                   ((float*)Cp)[(size_t)mg * N + n] = val;
        }
    }
}

// ---------------------------------------------------------------------------
// One recurrence step. Block (j, a), 64 threads. Column-j formulation:
//   v[m]   = beta[m] * sum_p R[m][j][p] * H[m][p]        (thread m)
//   out[k] = alpha[j] * sum_m L[j][k][m] * v[m] + X[k*64+j]  (thread k)
// Xc is the per-chunk X buffer; the h value overwrites X in place (same
// element read-then-write within a thread), becoming the bf16 h-history
// consumed by the Y GEMM.
// ---------------------------------------------------------------------------
__global__ __launch_bounds__(64) void step_kernel(
    const float* __restrict__ Hin, float* __restrict__ Hout,
    const float* __restrict__ Rm, const float* __restrict__ Lm,
    const float* __restrict__ alpha, const float* __restrict__ beta,
    bf16* __restrict__ Xc, int t, int t0, int tch)
{
    __shared__ float vsh[64];
    int j = blockIdx.x, a = blockIdx.y, tid = threadIdx.x;
    size_t mrow = (size_t)a * 2048 + t;            // global gate row
    size_t mloc = (size_t)a * tch + (t - t0);      // chunk-local row

    const float4* R4 = (const float4*)(Rm + (size_t)tid * 4096 + (size_t)j * 64);
    const float4* H4 = (const float4*)(Hin + (size_t)a * 4096 + (size_t)tid * 64);
    float s = 0.f;
    #pragma unroll
    for (int p = 0; p < 16; ++p) {
        float4 r = R4[p], h = H4[p];
        s += r.x * h.x + r.y * h.y + r.z * h.z + r.w * h.w;
    }
    s *= beta[mrow * 64 + tid];
    vsh[tid] = s;
    __syncthreads();

    const float4* L4 = (const float4*)(Lm + (size_t)j * 4096 + (size_t)tid * 64);
    const float4* V4 = (const float4*)vsh;
    float o = 0.f;
    #pragma unroll
    for (int q = 0; q < 16; ++q) {
        float4 l = L4[q], vv = V4[q];
        o += l.x * vv.x + l.y * vv.y + l.z * vv.z + l.w * vv.w;
    }
    int n = tid * 64 + j;
    o = o * alpha[mrow * 64 + j] + __bfloat162float(Xc[mloc * 4096 + n]);
    Hout[(size_t)a * 4096 + n] = o;
    Xc[mloc * 4096 + n] = __float2bfloat16(o);
}

// ---------------------------------------------------------------------------
extern "C" void kernel_launch(void* const* d_in, const int* in_sizes, int n_in,
                              void* d_out, int out_size, void* d_ws, size_t ws_size,
                              hipStream_t stream)
{
    const float* u     = (const float*)d_in[0];   // (8, 2048, 1024)
    const float* Lskew = (const float*)d_in[1];   // (64, 64, 64)
    const float* Rskew = (const float*)d_in[2];
    const float* Wg_w  = (const float*)d_in[3];   // (128, 1024)
    const float* Wg_b  = (const float*)d_in[4];   // (128,)
    const float* WB_w  = (const float*)d_in[5];   // (4096, 1024)
    const float* WB_b  = (const float*)d_in[6];   // (4096,)
    const float* C_w   = (const float*)d_in[7];   // (1024, 4096)
    const float* Dv    = (const float*)d_in[8];   // (1024,)

    const int BATCH = 8, T = 2048, DM = 1024, NN = 4096, BB = 64;
    const int TCH = 256;                 // timesteps per chunk
    const int NCH = T / TCH;             // 8 chunks
    const int CROWS = BATCH * TCH;       // 2048 local rows per chunk

    char* ws = (char*)d_ws;
    size_t off = 0;
    auto alloc = [&](size_t bytes) -> void* {
        void* p = ws + off;
        off += (bytes + 255) & ~(size_t)255;
        return p;
    };
    float* dL  = (float*)alloc(sizeof(float) * BB * BB * BB);        // 1 MB
    float* dR  = (float*)alloc(sizeof(float) * BB * BB * BB);        // 1 MB
    float* dAl = (float*)alloc(sizeof(float) * (size_t)BATCH * T * BB); // 4 MB
    float* dBe = (float*)alloc(sizeof(float) * (size_t)BATCH * T * BB); // 4 MB
    bf16*  dXc = (bf16*) alloc(sizeof(bf16)  * (size_t)CROWS * NN);  // 16 MB
    float* dH0 = (float*)alloc(sizeof(float) * BATCH * NN);          // 128 KB
    float* dH1 = (float*)alloc(sizeof(float) * BATCH * NN);          // 128 KB
    if (off > ws_size) return;  // needs ~26.5 MB

    // Phase 0: Cayley L,R
    hipLaunchKernelGGL(cayley_kernel, dim3(128), dim3(256), 0, stream, Lskew, Rskew, dL, dR);
    // Phase 1: gates for all (t, a)
    hipLaunchKernelGGL(gates_kernel, dim3(T / 8, BATCH), dim3(256), 0, stream,
                       u, Wg_w, Wg_b, dAl, dBe);
    // Phase 2: zero initial state
    hipMemsetAsync(dH0, 0, sizeof(float) * BATCH * NN, stream);

    float* hb[2] = {dH0, dH1};
    for (int c = 0; c < NCH; ++c) {
        int t0 = c * TCH;
        // X chunk = u_rows @ WB_w^T + WB_b  (local M=2048, N=4096, K=1024) -> bf16
        hipLaunchKernelGGL((gemm_nt_kernel<0, 1, 1, 0>),
                           dim3(NN / 64, CROWS / 64), dim3(256), 0, stream,
                           (const void*)u, WB_w, WB_b, (void*)dXc,
                           NN, DM, (const float*)nullptr, (const float*)nullptr,
                           t0, TCH, T);
        // sequential scan over this chunk; h overwrites X in place
        for (int tt = 0; tt < TCH; ++tt) {
            int t = t0 + tt;
            hipLaunchKernelGGL(step_kernel, dim3(64, BATCH), dim3(64), 0, stream,
                               hb[t & 1], hb[(t + 1) & 1], dR, dL, dAl, dBe,
                               dXc, t, t0, TCH);
        }
        // Y chunk = h_rows @ C_w^T + D*u_rows  (local M=2048, N=1024, K=4096) -> f32 d_out
        hipLaunchKernelGGL((gemm_nt_kernel<1, 0, 0, 1>),
                           dim3(DM / 64, CROWS / 64), dim3(256), 0, stream,
                           (const void*)dXc, C_w, (const float*)nullptr, (void*)d_out,
                           DM, NN, Dv, u,
                           t0, TCH, T);
    }
}